// Round 6
// baseline (1245.636 us; speedup 1.0000x reference)
//
#include <hip/hip_runtime.h>

#define N_NODES 20000
#define N_EDGES 100000
#define CIN     64
#define A_DIM   32
#define CCH     256
#define NBOX    128
#define FD      1024
#define HID     1024
#define OUT_STRIDE 2048

typedef __attribute__((ext_vector_type(8))) short          short8;
typedef __attribute__((ext_vector_type(8))) unsigned short ushort8;
typedef __attribute__((ext_vector_type(4))) unsigned short ushort4v;
typedef __attribute__((ext_vector_type(4))) float          floatx4;

#define ASTR 72   // shorts; 144B row stride -> conflict-free stores AND frag reads

__device__ __forceinline__ unsigned short f2bf(float f) {
    unsigned int u = __float_as_uint(f);
    u += 0x7fff + ((u >> 16) & 1);
    return (unsigned short)(u >> 16);
}
__device__ __forceinline__ float bf2f(unsigned short h) {
    return __uint_as_float(((unsigned int)h) << 16);
}

__device__ __forceinline__ void pack16(const float* __restrict__ p,
                                       ushort8& h0, ushort8& h1) {
    const float4* q = (const float4*)p;
    float4 a = q[0], b = q[1], c = q[2], d = q[3];
    h0 = (ushort8){f2bf(a.x), f2bf(a.y), f2bf(a.z), f2bf(a.w),
                   f2bf(b.x), f2bf(b.y), f2bf(b.z), f2bf(b.w)};
    h1 = (ushort8){f2bf(c.x), f2bf(c.y), f2bf(c.z), f2bf(c.w),
                   f2bf(d.x), f2bf(d.y), f2bf(d.z), f2bf(d.w)};
}

// ---------------------------------------------------------------------------
// bf16 MFMA GEMM, 128x128 tile, BK=64. A = [a0 | a1] raw bf16 (C0 % 32 == 0,
// K % 32 == 0), or fp32 source afp with optional row remap ridx (gather+conv
// in staging). B = bf16 Wt[n][k]. Epilogue: +bias, optional relu -> fp32 out
// and/or bf16 out. rmode: 0 = linear (sob/oob), 1 = R-pack (8 rows of 256
// shorts per 4096-short slab), 2 = pq-pack (4 rows of 512 shorts per slab).
// ---------------------------------------------------------------------------
__global__ __launch_bounds__(256) void mfma_bt(
    const unsigned short* __restrict__ a0, int s0, int o0, int C0,
    const unsigned short* __restrict__ a1, int s1, int o1,
    const float* __restrict__ afp, const int* __restrict__ ridx,
    const unsigned short* __restrict__ Wt, const float* __restrict__ bias,
    int do_relu,
    float* __restrict__ outf, int sof, int oof,
    unsigned short* __restrict__ outb, int sob, int oob, int rmode,
    int M, int K, int nbc)
{
    __shared__ __align__(16) unsigned short As[128 * ASTR];
    __shared__ __align__(16) unsigned short Bs[128 * ASTR];

    const int tid  = threadIdx.x;
    const int rb   = blockIdx.x / nbc, cb = blockIdx.x % nbc;
    const int r0   = rb * 128, c0 = cb * 128;
    const int wave = tid >> 6, lane = tid & 63;
    const int quad = lane >> 4, l16 = lane & 15;
    const int wm   = (wave & 1) * 64, wn = (wave >> 1) * 64;
    const int sr   = tid & 127;          // stage row
    const int h    = tid >> 7;           // stage 32-short half (0|1)

    floatx4 acc[4][4];
    #pragma unroll
    for (int i = 0; i < 4; ++i)
        #pragma unroll
        for (int j = 0; j < 4; ++j) acc[i][j] = (floatx4){0.f, 0.f, 0.f, 0.f};

    const int gr = r0 + sr;
    const int gn = c0 + sr;
    const ushort8 z8 = (ushort8){0,0,0,0,0,0,0,0};

    for (int k0 = 0; k0 < K; k0 += 64) {
        const int kb = k0 + h * 32;      // this thread's 32-short chunk start

        ushort8 v0 = z8, v1 = z8, v2 = z8, v3 = z8;
        if (gr < M && kb < K) {
            if (afp) {
                const int ar = ridx ? ridx[gr] : gr;
                const float* s = afp + (long)ar * s0 + o0 + kb;
                pack16(s, v0, v1);
                pack16(s + 16, v2, v3);
            } else {
                const ushort8* p = (kb < C0)
                    ? (const ushort8*)(a0 + (long)gr * s0 + o0 + kb)
                    : (const ushort8*)(a1 + (long)gr * s1 + o1 + (kb - C0));
                v0 = p[0]; v1 = p[1]; v2 = p[2]; v3 = p[3];
            }
        }
        {
            unsigned short* d = &As[sr * ASTR + h * 32];
            *(ushort8*)(d)      = v0;
            *(ushort8*)(d + 8)  = v1;
            *(ushort8*)(d + 16) = v2;
            *(ushort8*)(d + 24) = v3;
        }

        ushort8 w0 = z8, w1 = z8, w2 = z8, w3 = z8;
        if (kb < K) {
            const ushort8* p = (const ushort8*)(Wt + (long)gn * K + kb);
            w0 = p[0]; w1 = p[1]; w2 = p[2]; w3 = p[3];
        }
        {
            unsigned short* d = &Bs[sr * ASTR + h * 32];
            *(ushort8*)(d)      = w0;
            *(ushort8*)(d + 8)  = w1;
            *(ushort8*)(d + 16) = w2;
            *(ushort8*)(d + 24) = w3;
        }

        __syncthreads();

        #pragma unroll
        for (int c = 0; c < 2; ++c) {
            short8 af[4], bfr[4];
            #pragma unroll
            for (int mt = 0; mt < 4; ++mt)
                af[mt] = *(const short8*)(&As[(wm + mt * 16 + l16) * ASTR + c * 32 + quad * 8]);
            #pragma unroll
            for (int nt = 0; nt < 4; ++nt)
                bfr[nt] = *(const short8*)(&Bs[(wn + nt * 16 + l16) * ASTR + c * 32 + quad * 8]);
            #pragma unroll
            for (int mt = 0; mt < 4; ++mt)
                #pragma unroll
                for (int nt = 0; nt < 4; ++nt)
                    acc[mt][nt] = __builtin_amdgcn_mfma_f32_16x16x32_bf16(
                        af[mt], bfr[nt], acc[mt][nt], 0, 0, 0);
        }
        __syncthreads();
    }

    #pragma unroll
    for (int nt = 0; nt < 4; ++nt) {
        const int gc = c0 + wn + nt * 16 + l16;
        const float bv = bias ? bias[gc] : 0.f;
        #pragma unroll
        for (int mt = 0; mt < 4; ++mt) {
            #pragma unroll
            for (int reg = 0; reg < 4; ++reg) {
                const int grr = r0 + wm + mt * 16 + quad * 4 + reg;
                if (grr < M) {
                    float v = acc[mt][nt][reg] + bv;
                    if (do_relu) v = fmaxf(v, 0.f);
                    if (outf) outf[(long)grr * sof + oof + gc] = v;
                    if (outb) {
                        long idx;
                        if (rmode == 1)      idx = (long)(grr >> 3) * 4096 + (grr & 7) * 256 + gc;
                        else if (rmode == 2) idx = (long)(grr >> 2) * 4096 + (grr & 3) * 512 + gc;
                        else                 idx = (long)grr * sob + oob + gc;
                        outb[idx] = f2bf(v);
                    }
                }
            }
        }
    }
}

// ---------------------------------------------------------------------------
// Aggregation: one wave per dst node. f_out[d] = sum_e relu(P[d]+Q[src]+R[e]+b)
// * ew[e]  (+ residual).  Writes fp32 f to d_out and bf16 to featsb.
// pq packed 4 nodes per 4096-short slab (shorts [0,2048) of out rows
// [12500,17500)); R packed 8 edges per slab (rows [0,12500)).
// ---------------------------------------------------------------------------
__global__ __launch_bounds__(256) void agg_kernel(
    const unsigned short* __restrict__ pqb,  // packed pq base
    const int* __restrict__ rowptr,
    const int* __restrict__ ssrc,
    const float* __restrict__ sew,
    const float* __restrict__ outbase,       // d_out base: R scratch + residual
    const float* __restrict__ bias,
    float* __restrict__ out, int fofs, int rofs,
    unsigned short* __restrict__ foutb)      // featsb + layer col offset
{
    const int wid  = (blockIdx.x * blockDim.x + threadIdx.x) >> 6;
    const int lane = threadIdx.x & 63;
    if (wid >= N_NODES) return;
    const int c = lane * 4;

    const ushort4v p4 = *(const ushort4v*)(pqb + (long)(wid >> 2) * 4096 + (wid & 3) * 512 + c);
    const float4 bb = *(const float4*)(bias + c);
    float pb[4] = {bf2f(p4[0]) + bb.x, bf2f(p4[1]) + bb.y,
                   bf2f(p4[2]) + bb.z, bf2f(p4[3]) + bb.w};
    float acc[4] = {0.f, 0.f, 0.f, 0.f};

    const int sEnd = rowptr[wid + 1];
    for (int s = rowptr[wid]; s < sEnd; ++s) {
        const int   srcn = ssrc[s];
        const float w    = sew[s];
        const ushort4v q4 = *(const ushort4v*)(pqb + (long)(srcn >> 2) * 4096
                                               + (srcn & 3) * 512 + 256 + c);
        const unsigned short* rp =
            (const unsigned short*)(outbase + (long)(s >> 3) * OUT_STRIDE) + (s & 7) * 256 + c;
        const ushort4v r4 = *(const ushort4v*)rp;
        #pragma unroll
        for (int j = 0; j < 4; ++j)
            acc[j] += fmaxf(pb[j] + bf2f(q4[j]) + bf2f(r4[j]), 0.f) * w;
    }
    if (rofs >= 0) {
        const float4 f4 = *(const float4*)(outbase + (long)wid * OUT_STRIDE + rofs + c);
        acc[0] += f4.x; acc[1] += f4.y; acc[2] += f4.z; acc[3] += f4.w;
    }
    float4 o; o.x = acc[0]; o.y = acc[1]; o.z = acc[2]; o.w = acc[3];
    *(float4*)(out + (long)wid * OUT_STRIDE + fofs + c) = o;
    ushort4v ob = (ushort4v){f2bf(acc[0]), f2bf(acc[1]), f2bf(acc[2]), f2bf(acc[3])};
    *(ushort4v*)(foutb + (long)wid * FD + c) = ob;
}

// ---------------------------------------------------------------------------
// Weight / input prep
// ---------------------------------------------------------------------------
__global__ void wpq_prep(const float* __restrict__ W, unsigned short* __restrict__ Wpq, int F) {
    int i = blockIdx.x * blockDim.x + threadIdx.x;
    if (i < 512 * F) {
        int nn = i / F, k = i % F;
        float v = (nn < 256) ? (W[k * 256 + nn] - W[(F + k) * 256 + nn])
                             : W[(F + k) * 256 + (nn - 256)];
        Wpq[(long)nn * F + k] = f2bf(v);
    }
}

__global__ __launch_bounds__(256) void transpose_tiled(
    const float* __restrict__ W, unsigned short* __restrict__ Wt, int K, int N) {
    __shared__ float t[32][33];
    const int ki = blockIdx.y * 32, ni = blockIdx.x * 32;
    const int tx = threadIdx.x & 31, ty = threadIdx.x >> 5;
    #pragma unroll
    for (int p = 0; p < 4; ++p) {
        int k = ki + ty + p * 8;
        t[ty + p * 8][tx] = (k < K && ni + tx < N) ? W[(long)k * N + ni + tx] : 0.f;
    }
    __syncthreads();
    #pragma unroll
    for (int p = 0; p < 4; ++p) {
        int n = ni + ty + p * 8;
        if (n < N && ki + tx < K)
            Wt[(long)n * K + ki + tx] = f2bf(t[tx][ty + p * 8]);
    }
}

__global__ void conv_bf16(const float* __restrict__ src, unsigned short* __restrict__ dst, long n) {
    long i = (long)blockIdx.x * blockDim.x + threadIdx.x;
    if (i < n) dst[i] = f2bf(src[i]);
}

// ---------------------------------------------------------------------------
// CSR build
// ---------------------------------------------------------------------------
__global__ void zero_int(int* p, int n) {
    int i = blockIdx.x * blockDim.x + threadIdx.x;
    if (i < n) p[i] = 0;
}
__global__ void hist_kernel(const int* __restrict__ keys, int n, int* __restrict__ cnt) {
    int i = blockIdx.x * blockDim.x + threadIdx.x;
    if (i < n) atomicAdd(&cnt[keys[i]], 1);
}
__global__ __launch_bounds__(1024) void scan_kernel(const int* __restrict__ cnt,
                                                    int* __restrict__ rowptr,
                                                    int* __restrict__ ofs, int n) {
    __shared__ int part[1024];
    const int tid = threadIdx.x;
    const int chunk = (n + 1023) >> 10;
    int s = 0;
    for (int j = 0; j < chunk; ++j) {
        int i = tid * chunk + j;
        if (i < n) s += cnt[i];
    }
    part[tid] = s; __syncthreads();
    for (int d = 1; d < 1024; d <<= 1) {
        int v = (tid >= d) ? part[tid - d] : 0;
        __syncthreads();
        part[tid] += v;
        __syncthreads();
    }
    int run = (tid > 0) ? part[tid - 1] : 0;
    for (int j = 0; j < chunk; ++j) {
        int i = tid * chunk + j;
        if (i < n) { rowptr[i] = run; ofs[i] = run; run += cnt[i]; }
    }
    if (tid == 1023) rowptr[n] = part[1023];
}
__global__ void scatter_edges(const int* __restrict__ src, const int* __restrict__ dst,
                              const float* __restrict__ ew, int* __restrict__ ofs,
                              int* __restrict__ ssrc, float* __restrict__ sew,
                              int* __restrict__ seid) {
    int e = blockIdx.x * blockDim.x + threadIdx.x;
    if (e < N_EDGES) {
        int pos = atomicAdd(&ofs[dst[e]], 1);
        ssrc[pos] = src[e];
        sew[pos]  = ew[e];
        seid[pos] = e;
    }
}
__global__ void scatter_box(const int* __restrict__ bbox, int* __restrict__ ofs,
                            int* __restrict__ snode) {
    int i = blockIdx.x * blockDim.x + threadIdx.x;
    if (i < N_NODES) {
        int pos = atomicAdd(&ofs[bbox[i]], 1);
        snode[pos] = i;
    }
}

// ---------------------------------------------------------------------------
// Per-layer box sum (CSR, no atomics): fs is [N,256] bf16; writes 256-col
// stripe of box_sums [128,1024] fp32 (direct store, full coverage).
// ---------------------------------------------------------------------------
__global__ __launch_bounds__(256) void box_sum_csr(
    const unsigned short* __restrict__ fs, const int* __restrict__ bptr,
    const int* __restrict__ snode, float* __restrict__ sums, int col_ofs)
{
    const int b = blockIdx.x;
    const int c = threadIdx.x;
    const int s0 = bptr[b], s1 = bptr[b + 1];
    float sum = 0.f;
    for (int s = s0; s < s1; ++s)
        sum += bf2f(fs[(long)snode[s] * 256 + c]);
    sums[(long)b * FD + col_ofs + c] = sum;
}

__global__ void box_finish(const float* __restrict__ sums, const int* __restrict__ bptr,
                           float* __restrict__ out_super,
                           unsigned short* __restrict__ fsmeanb)
{
    int i = blockIdx.x * blockDim.x + threadIdx.x;
    if (i < NBOX * FD) {
        int b = i >> 10, c = i & 1023;
        float cnt = (float)(bptr[b + 1] - bptr[b]);
        float mean = sums[i] / fmaxf(cnt, 1.f);
        out_super[(long)b * OUT_STRIDE + HID + c] = mean;
        fsmeanb[i] = f2bf(mean);
    }
}

// ---------------------------------------------------------------------------
extern "C" void kernel_launch(void* const* d_in, const int* in_sizes, int n_in,
                              void* d_out, int out_size, void* d_ws, size_t ws_size,
                              hipStream_t stream) {
    const float* x      = (const float*)d_in[0];
    const int*   edges  = (const int*)d_in[1];
    const float* ew     = (const float*)d_in[2];
    const float* ea     = (const float*)d_in[3];
    const int*   bbox   = (const int*)d_in[4];
    const float* W_msg0 = (const float*)d_in[6];
    const float* b_msg0 = (const float*)d_in[7];
    const float* W_sup0 = (const float*)d_in[8];
    const float* b_sup0 = (const float*)d_in[9];
    const float* W_msg  = (const float*)d_in[10];
    const float* b_msg  = (const float*)d_in[11];
    const float* W_sup  = (const float*)d_in[12];
    const float* b_sup  = (const float*)d_in[13];
    const float* W_fuse = (const float*)d_in[14];
    const float* b_fuse = (const float*)d_in[15];
    const float* W_fsup = (const float*)d_in[16];
    const float* b_fsup = (const float*)d_in[17];

    float* out       = (float*)d_out;
    float* out_super = out + (long)N_NODES * OUT_STRIDE;

    // d_out dead-region scratch (fp32 cols [0,1024) == shorts [0,2048) of each
    // 4096-short row slab; feature cols [1024,2048) are NEVER touched):
    //   R:  8 edges/slab * 256 shorts, slabs (rows) [0,12500)
    //   pq: 4 nodes/slab * 512 shorts, slabs [12500,17500)
    unsigned short* Rb  = (unsigned short*)out;
    unsigned short* pqb = (unsigned short*)out + (long)12500 * 4096;

    // ---- workspace (~72 MB) ----
    char* w = (char*)d_ws;
    auto alloc = [&](size_t bytes) { char* p = w; w += (bytes + 63) & ~63ULL; return p; };
    unsigned short* featsb  = (unsigned short*)alloc((size_t)N_NODES * FD * 2);
    unsigned short* fs_ping = (unsigned short*)alloc((size_t)N_NODES * CCH * 2);
    unsigned short* fs_pong = (unsigned short*)alloc((size_t)N_NODES * CCH * 2);
    unsigned short* xb      = (unsigned short*)alloc((size_t)N_NODES * CIN * 2);
    unsigned short* wpq0    = (unsigned short*)alloc((size_t)512 * CIN * 2);
    unsigned short* wpq     = (unsigned short*)alloc((size_t)3 * 512 * CCH * 2);
    unsigned short* wtr     = (unsigned short*)alloc((size_t)4 * 256 * 32 * 2);
    unsigned short* wt_sup0 = (unsigned short*)alloc((size_t)256 * 320 * 2);
    unsigned short* wt_sup  = (unsigned short*)alloc((size_t)3 * 256 * 512 * 2);
    unsigned short* wt_fuse = (unsigned short*)alloc((size_t)1024 * 1024 * 2);
    unsigned short* wt_fsup = (unsigned short*)alloc((size_t)1024 * 1024 * 2);
    unsigned short* fsmeanb = (unsigned short*)alloc((size_t)NBOX * FD * 2);
    float* box_sums   = (float*)alloc((size_t)NBOX * FD * 4);
    float* sew        = (float*)alloc((size_t)N_EDGES * 4);
    int* cnt          = (int*)alloc((size_t)(N_NODES + 1) * 4);
    int* rowptr       = (int*)alloc((size_t)(N_NODES + 1) * 4);
    int* ofs          = (int*)alloc((size_t)(N_NODES + 1) * 4);
    int* ssrc         = (int*)alloc((size_t)N_EDGES * 4);
    int* seid         = (int*)alloc((size_t)N_EDGES * 4);
    int* bcnt         = (int*)alloc(129 * 4);
    int* bptr         = (int*)alloc(129 * 4);
    int* bofs         = (int*)alloc(129 * 4);
    int* snode        = (int*)alloc((size_t)N_NODES * 4);

    const int* srcp = edges;
    const int* dstp = edges + N_EDGES;

    // ---- weight prep ----
    wpq_prep<<<(512 * CIN + 255) / 256, 256, 0, stream>>>(W_msg0, wpq0, CIN);
    for (int i = 0; i < 3; ++i)
        wpq_prep<<<(512 * CCH + 255) / 256, 256, 0, stream>>>(
            W_msg + (long)i * 544 * 256, wpq + (long)i * 512 * CCH, CCH);
    transpose_tiled<<<dim3(8, 1), 256, 0, stream>>>(W_msg0 + 2 * CIN * 256, wtr, 32, 256);
    for (int i = 0; i < 3; ++i)
        transpose_tiled<<<dim3(8, 1), 256, 0, stream>>>(
            W_msg + (long)i * 544 * 256 + 2 * CCH * 256, wtr + (long)(i + 1) * 256 * 32, 32, 256);
    transpose_tiled<<<dim3(8, 10), 256, 0, stream>>>(W_sup0, wt_sup0, 320, 256);
    for (int i = 0; i < 3; ++i)
        transpose_tiled<<<dim3(8, 16), 256, 0, stream>>>(
            W_sup + (long)i * 512 * 256, wt_sup + (long)i * 256 * 512, 512, 256);
    transpose_tiled<<<dim3(32, 32), 256, 0, stream>>>(W_fuse, wt_fuse, 1024, 1024);
    transpose_tiled<<<dim3(32, 32), 256, 0, stream>>>(W_fsup, wt_fsup, 1024, 1024);
    conv_bf16<<<(N_NODES * CIN + 255) / 256, 256, 0, stream>>>(x, xb, (long)N_NODES * CIN);

    // ---- CSR build ----
    zero_int<<<(N_NODES + 256) / 256, 256, 0, stream>>>(cnt, N_NODES + 1);
    zero_int<<<1, 256, 0, stream>>>(bcnt, 129);
    hist_kernel<<<(N_EDGES + 255) / 256, 256, 0, stream>>>(dstp, N_EDGES, cnt);
    hist_kernel<<<(N_NODES + 255) / 256, 256, 0, stream>>>(bbox, N_NODES, bcnt);
    scan_kernel<<<1, 1024, 0, stream>>>(cnt, rowptr, ofs, N_NODES);
    scan_kernel<<<1, 1024, 0, stream>>>(bcnt, bptr, bofs, NBOX);
    scatter_edges<<<(N_EDGES + 255) / 256, 256, 0, stream>>>(srcp, dstp, ew, ofs, ssrc, sew, seid);
    scatter_box<<<(N_NODES + 255) / 256, 256, 0, stream>>>(bbox, bofs, snode);

    const int GRB = (N_NODES + 127) / 128;   // 157
    const int GEB = (N_EDGES + 127) / 128;   // 782

    unsigned short* fs_cur = fs_ping;
    unsigned short* fs_prv = fs_pong;

    // ---- head block ----
    mfma_bt<<<GRB * 4, 256, 0, stream>>>(xb, CIN, 0, CIN, nullptr, 0, 0,
        nullptr, nullptr, wpq0, nullptr, 0,
        nullptr, 0, 0, pqb, 0, 0, 2, N_NODES, CIN, 4);
    mfma_bt<<<GEB * 2, 256, 0, stream>>>(nullptr, A_DIM, 0, 0, nullptr, 0, 0,
        ea, seid, wtr, nullptr, 0,
        nullptr, 0, 0, Rb, 0, 0, 1, N_EDGES, A_DIM, 2);
    agg_kernel<<<(N_NODES + 3) / 4, 256, 0, stream>>>(pqb, rowptr, ssrc, sew, out,
                                                      b_msg0, out, HID, -1, featsb);
    mfma_bt<<<GRB * 2, 256, 0, stream>>>(featsb, FD, 0, CCH, xb, CIN, 0,
        nullptr, nullptr, wt_sup0, b_sup0, 1,
        nullptr, 0, 0, fs_cur, CCH, 0, 0, N_NODES, CCH + CIN, 2);
    box_sum_csr<<<NBOX, 256, 0, stream>>>(fs_cur, bptr, snode, box_sums, 0);

    // ---- ResBlocks ----
    for (int i = 0; i < 3; ++i) {
        const int fo = HID + CCH * (i + 1), fi = HID + CCH * i;
        unsigned short* t = fs_prv; fs_prv = fs_cur; fs_cur = t;

        mfma_bt<<<GRB * 4, 256, 0, stream>>>(featsb, FD, CCH * i, CCH, nullptr, 0, 0,
            nullptr, nullptr, wpq + (long)i * 512 * CCH, nullptr, 0,
            nullptr, 0, 0, pqb, 0, 0, 2, N_NODES, CCH, 4);
        mfma_bt<<<GEB * 2, 256, 0, stream>>>(nullptr, A_DIM, 0, 0, nullptr, 0, 0,
            ea, seid, wtr + (long)(i + 1) * 256 * 32, nullptr, 0,
            nullptr, 0, 0, Rb, 0, 0, 1, N_EDGES, A_DIM, 2);
        agg_kernel<<<(N_NODES + 3) / 4, 256, 0, stream>>>(pqb, rowptr, ssrc, sew, out,
            b_msg + i * CCH, out, fo, fi, featsb + CCH * (i + 1));
        mfma_bt<<<GRB * 2, 256, 0, stream>>>(featsb, FD, CCH * (i + 1), CCH,
            fs_prv, CCH, 0,
            nullptr, nullptr, wt_sup + (long)i * 256 * 512, b_sup + i * CCH, 1,
            nullptr, 0, 0, fs_cur, CCH, 0, 0, N_NODES, 2 * CCH, 2);
        box_sum_csr<<<NBOX, 256, 0, stream>>>(fs_cur, bptr, snode, box_sums, CCH * (i + 1));
    }

    // ---- fusion (clobbers R/pq scratch -> all dead by now) ----
    mfma_bt<<<GRB * 8, 256, 0, stream>>>(featsb, FD, 0, FD, nullptr, 0, 0,
        nullptr, nullptr, wt_fuse, b_fuse, 1,
        out, OUT_STRIDE, 0, nullptr, 0, 0, 0, N_NODES, FD, 8);

    // ---- super path ----
    box_finish<<<(NBOX * FD + 255) / 256, 256, 0, stream>>>(box_sums, bptr,
                                                            out_super, fsmeanb);
    mfma_bt<<<8, 256, 0, stream>>>(fsmeanb, FD, 0, FD, nullptr, 0, 0,
        nullptr, nullptr, wt_fsup, b_fsup, 1,
        out_super, OUT_STRIDE, 0, nullptr, 0, 0, 0, NBOX, FD, 8);
}